// Round 1
// baseline (563.551 us; speedup 1.0000x reference)
//
#include <hip/hip_runtime.h>
#include <hip/hip_bf16.h>
#include <stdint.h>

typedef __attribute__((ext_vector_type(8))) short short8;
typedef __attribute__((ext_vector_type(4))) float f32x4;

static constexpr int kN   = 262144;
static constexpr int kD   = 256;
static constexpr int kSeg = 1024;

__device__ __forceinline__ unsigned short f2bf(float f) {
    union { float f; unsigned int u; } v; v.f = f;
    unsigned int u = v.u;
    return (unsigned short)((u + 0x7FFFu + ((u >> 16) & 1u)) >> 16);  // RNE
}

// Pack W1 [256x256] f32 (row-major, k-major) into bf16 MFMA B-fragment order:
// packed[((j*8+kk)*64 + lane)*8 + i] = bf16(W1[kk*32 + (lane>>4)*8 + i][j*16 + (lane&15)])
__global__ void pack_w1_kernel(const float* __restrict__ W1, unsigned short* __restrict__ packed) {
    int t = blockIdx.x * blockDim.x + threadIdx.x;  // 8192 threads
    int l = t & 63, kk = (t >> 6) & 7, j = t >> 9;
    int col = j * 16 + (l & 15);
    int kb  = kk * 32 + ((l >> 4) & 3) * 8;
    short8 s;
#pragma unroll
    for (int i = 0; i < 8; ++i) s[i] = (short)f2bf(W1[(size_t)(kb + i) * kD + col]);
    *reinterpret_cast<short8*>(packed + (size_t)t * 8) = s;
}

// scores[i] = relu(x[i]@W1 + b1) @ W2 + b2, via bf16 MFMA. 4 waves/block, 64 rows/wave.
__global__ __launch_bounds__(256) void score_kernel(
    const float* __restrict__ x, const unsigned short* __restrict__ packedW1,
    const float* __restrict__ b1, const float* __restrict__ W2,
    const float* __restrict__ b2, float* __restrict__ scores)
{
    const int lane = threadIdx.x & 63;
    const int wave = threadIdx.x >> 6;
    const int r0   = lane & 15;       // A row within 16-row tile / C col within tile
    const int q    = lane >> 4;       // quarter
    const int base_row = blockIdx.x * 256 + wave * 64;

    // A fragments: a[rt][kk][i] = bf16(x[base+rt*16+r0][kk*32 + q*8 + i])
    short8 afrag[4][8];
#pragma unroll
    for (int rt = 0; rt < 4; ++rt) {
        const float* xp = x + (size_t)(base_row + rt * 16 + r0) * kD + q * 8;
#pragma unroll
        for (int kk = 0; kk < 8; ++kk) {
            f32x4 v0 = *reinterpret_cast<const f32x4*>(xp + kk * 32);
            f32x4 v1 = *reinterpret_cast<const f32x4*>(xp + kk * 32 + 4);
            short8 a;
            a[0] = (short)f2bf(v0[0]); a[1] = (short)f2bf(v0[1]);
            a[2] = (short)f2bf(v0[2]); a[3] = (short)f2bf(v0[3]);
            a[4] = (short)f2bf(v1[0]); a[5] = (short)f2bf(v1[1]);
            a[6] = (short)f2bf(v1[2]); a[7] = (short)f2bf(v1[3]);
            afrag[rt][kk] = a;
        }
    }

    float spart[4][4];
#pragma unroll
    for (int rt = 0; rt < 4; ++rt)
#pragma unroll
        for (int r = 0; r < 4; ++r) spart[rt][r] = 0.f;

    const short8* bbase = reinterpret_cast<const short8*>(packedW1);
    for (int j = 0; j < 16; ++j) {              // 16 column-tiles of 16
        short8 bfrag[8];
        const short8* bp = bbase + (size_t)(j * 8) * 64 + lane;
#pragma unroll
        for (int kk = 0; kk < 8; ++kk) bfrag[kk] = bp[(size_t)kk * 64];

        const int col   = j * 16 + r0;
        const float b1c = b1[col];
        const float w2c = W2[col];
#pragma unroll
        for (int rt = 0; rt < 4; ++rt) {
            f32x4 acc = {0.f, 0.f, 0.f, 0.f};
#pragma unroll
            for (int kk = 0; kk < 8; ++kk)
                acc = __builtin_amdgcn_mfma_f32_16x16x32_bf16(afrag[rt][kk], bfrag[kk], acc, 0, 0, 0);
            // C layout: col = lane&15 (= our `col`), row = q*4 + r within tile
#pragma unroll
            for (int r = 0; r < 4; ++r) {
                float h = fmaxf(acc[r] + b1c, 0.f);
                spart[rt][r] = fmaf(h, w2c, spart[rt][r]);
            }
        }
    }

    const float bias2 = b2[0];
#pragma unroll
    for (int rt = 0; rt < 4; ++rt)
#pragma unroll
        for (int r = 0; r < 4; ++r) {
            float v = spart[rt][r];
            v += __shfl_xor(v, 1);
            v += __shfl_xor(v, 2);
            v += __shfl_xor(v, 4);
            v += __shfl_xor(v, 8);   // sum over the 16 lanes sharing q
            if (r0 == 0) scores[base_row + rt * 16 + q * 4 + r] = v + bias2;
        }
}

// One block per segment: bounds via binary search (batch sorted), max (clamped >=0),
// exp-sum, then per-column weighted accumulation of x.
__global__ __launch_bounds__(256) void pool_kernel(
    const float* __restrict__ x, const int* __restrict__ batch,
    const float* __restrict__ scores, float* __restrict__ out)
{
    const int g    = blockIdx.x;
    const int tid  = threadIdx.x;
    const int lane = tid & 63;
    const int wave = tid >> 6;

    __shared__ int   s_bounds[2];
    __shared__ float red[4];

    if (tid < 2) {
        int target = g + tid;
        int lo = 0, hi = kN;
        while (lo < hi) {
            int mid = (lo + hi) >> 1;
            if (batch[mid] < target) lo = mid + 1; else hi = mid;
        }
        s_bounds[tid] = lo;
    }
    __syncthreads();
    const int lo = s_bounds[0], hi = s_bounds[1];

    // segment max, clamped at >= 0 (torch scatter-amax-into-zeros semantics)
    float m = 0.f;
    for (int i = lo + tid; i < hi; i += 256) m = fmaxf(m, scores[i]);
#pragma unroll
    for (int off = 32; off > 0; off >>= 1) m = fmaxf(m, __shfl_xor(m, off));
    if (lane == 0) red[wave] = m;
    __syncthreads();
    m = fmaxf(fmaxf(red[0], red[1]), fmaxf(red[2], red[3]));
    __syncthreads();

    // sum of exp
    float sum = 0.f;
    for (int i = lo + tid; i < hi; i += 256) sum += __expf(scores[i] - m);
#pragma unroll
    for (int off = 32; off > 0; off >>= 1) sum += __shfl_xor(sum, off);
    if (lane == 0) red[wave] = sum;
    __syncthreads();
    sum = red[0] + red[1] + red[2] + red[3];

    // weighted accumulation: thread owns column `tid`
    float acc = 0.f;
    for (int i = lo; i < hi; ++i) {
        float w = __expf(scores[i] - m);
        acc = fmaf(x[(size_t)i * kD + tid], w, acc);
    }
    out[(size_t)g * kD + tid] = acc / (sum + 1e-9f);
}

extern "C" void kernel_launch(void* const* d_in, const int* in_sizes, int n_in,
                              void* d_out, int out_size, void* d_ws, size_t ws_size,
                              hipStream_t stream) {
    const float* x     = (const float*)d_in[0];
    const float* W1    = (const float*)d_in[1];
    const float* b1    = (const float*)d_in[2];
    const float* W2    = (const float*)d_in[3];
    const float* b2    = (const float*)d_in[4];
    const int*   batch = (const int*)d_in[5];
    float* out = (float*)d_out;

    unsigned short* packed = (unsigned short*)d_ws;              // 131072 B
    float* scores = (float*)((char*)d_ws + 131072);              // 1 MB

    pack_w1_kernel<<<32, 256, 0, stream>>>(W1, packed);
    score_kernel<<<kN / 256, 256, 0, stream>>>(x, packed, b1, W2, b2, scores);
    pool_kernel<<<kSeg, 256, 0, stream>>>(x, batch, scores, out);
}

// Round 2
// 461.017 us; speedup vs baseline: 1.2224x; 1.2224x over previous
//
#include <hip/hip_runtime.h>
#include <hip/hip_bf16.h>
#include <stdint.h>

typedef __attribute__((ext_vector_type(8))) short short8;
typedef __attribute__((ext_vector_type(4))) float f32x4;

static constexpr int kN   = 262144;
static constexpr int kD   = 256;
static constexpr int kSeg = 1024;
static constexpr int kRS  = 260;   // LDS row stride in f32 (+4 pad: 260%32=4 -> 2-way banks, free)

__device__ __forceinline__ unsigned short f2bf(float f) {
    union { float f; unsigned int u; } v; v.f = f;
    unsigned int u = v.u;
    return (unsigned short)((u + 0x7FFFu + ((u >> 16) & 1u)) >> 16);  // RNE
}

__device__ __forceinline__ void gload_lds16(const float* gsrc, float* lds_dst) {
    __builtin_amdgcn_global_load_lds(
        (const __attribute__((address_space(1))) void*)gsrc,
        (__attribute__((address_space(3))) void*)lds_dst,
        16, 0, 0);
}

// Pack W1 [256x256] f32 (row-major, k-major) into bf16 MFMA B-fragment order:
// packed[((j*8+kk)*64 + lane)*8 + i] = bf16(W1[kk*32 + (lane>>4)*8 + i][j*16 + (lane&15)])
__global__ void pack_w1_kernel(const float* __restrict__ W1, unsigned short* __restrict__ packed) {
    int t = blockIdx.x * blockDim.x + threadIdx.x;  // 8192 threads
    int l = t & 63, kk = (t >> 6) & 7, j = t >> 9;
    int col = j * 16 + (l & 15);
    int kb  = kk * 32 + ((l >> 4) & 3) * 8;
    short8 s;
#pragma unroll
    for (int i = 0; i < 8; ++i) s[i] = (short)f2bf(W1[(size_t)(kb + i) * kD + col]);
    *reinterpret_cast<short8*>(packed + (size_t)t * 8) = s;
}

// scores[i] = relu(x[i]@W1 + b1) @ W2 + b2.
// Block: 256 threads (4 waves), 32 rows. x tile staged f32 in LDS via global_load_lds.
// Each wave handles ALL 32 rows for its j-quarter (4 of 16 column-tiles); cross-wave
// reduce of the per-quarter partial scores through LDS.
__global__ __launch_bounds__(256, 4) void score_kernel(
    const float* __restrict__ x, const unsigned short* __restrict__ packedW1,
    const float* __restrict__ b1, const float* __restrict__ W2,
    const float* __restrict__ b2, float* __restrict__ scores)
{
    __shared__ float sx[32 * kRS];     // 33280 B
    __shared__ float sred[4][32];      // 512 B

    const int tid  = threadIdx.x;
    const int lane = tid & 63;
    const int wave = tid >> 6;         // 0..3 = j-quarter
    const int r0   = lane & 15;
    const int q    = lane >> 4;
    const int block_row = blockIdx.x * 32;

    // ---- stage 32 rows x 256 cols f32 into LDS; wave w stages rows w*8..w*8+7 ----
    {
        const float* src = x + (size_t)(block_row + wave * 8) * kD + lane * 4;
#pragma unroll
        for (int r = 0; r < 8; ++r)
            gload_lds16(src + (size_t)r * kD, &sx[(wave * 8 + r) * kRS]);
    }
    asm volatile("s_waitcnt vmcnt(0)" ::: "memory");
    __syncthreads();

    // ---- A fragments from LDS (each wave converts all 32 rows) ----
    // afrag[rt][kk][i] = bf16(x[block_row + rt*16 + r0][kk*32 + q*8 + i])
    short8 afrag[2][8];
#pragma unroll
    for (int rt = 0; rt < 2; ++rt) {
        const float* rp = &sx[(rt * 16 + r0) * kRS + q * 8];
#pragma unroll
        for (int kk = 0; kk < 8; ++kk) {
            f32x4 v0 = *reinterpret_cast<const f32x4*>(rp + kk * 32);
            f32x4 v1 = *reinterpret_cast<const f32x4*>(rp + kk * 32 + 4);
            short8 a;
            a[0] = (short)f2bf(v0[0]); a[1] = (short)f2bf(v0[1]);
            a[2] = (short)f2bf(v0[2]); a[3] = (short)f2bf(v0[3]);
            a[4] = (short)f2bf(v1[0]); a[5] = (short)f2bf(v1[1]);
            a[6] = (short)f2bf(v1[2]); a[7] = (short)f2bf(v1[3]);
            afrag[rt][kk] = a;
        }
    }

    // ---- j-quarter loop: 4 column-tiles, K fully registered ----
    float spart[2][4];
#pragma unroll
    for (int rt = 0; rt < 2; ++rt)
#pragma unroll
        for (int r = 0; r < 4; ++r) spart[rt][r] = 0.f;

    const short8* bbase = reinterpret_cast<const short8*>(packedW1);
#pragma unroll
    for (int jj = 0; jj < 4; ++jj) {
        const int j = wave * 4 + jj;
        short8 bfrag[8];
        const short8* bp = bbase + (size_t)(j * 8) * 64 + lane;
#pragma unroll
        for (int kk = 0; kk < 8; ++kk) bfrag[kk] = bp[(size_t)kk * 64];

        const int col   = j * 16 + r0;
        const float b1c = b1[col];
        const float w2c = W2[col];
#pragma unroll
        for (int rt = 0; rt < 2; ++rt) {
            f32x4 acc = {0.f, 0.f, 0.f, 0.f};
#pragma unroll
            for (int kk = 0; kk < 8; ++kk)
                acc = __builtin_amdgcn_mfma_f32_16x16x32_bf16(afrag[rt][kk], bfrag[kk], acc, 0, 0, 0);
            // C layout: col = lane&15 (= our `col`), row = q*4 + r within tile
#pragma unroll
            for (int r = 0; r < 4; ++r) {
                float h = fmaxf(acc[r] + b1c, 0.f);
                spart[rt][r] = fmaf(h, w2c, spart[rt][r]);
            }
        }
    }

    // ---- reduce 16 lanes sharing q, then cross-wave (j-quarter) reduce via LDS ----
#pragma unroll
    for (int rt = 0; rt < 2; ++rt)
#pragma unroll
        for (int r = 0; r < 4; ++r) {
            float v = spart[rt][r];
            v += __shfl_xor(v, 1);
            v += __shfl_xor(v, 2);
            v += __shfl_xor(v, 4);
            v += __shfl_xor(v, 8);
            if (r0 == 0) sred[wave][rt * 16 + q * 4 + r] = v;
        }
    __syncthreads();
    if (tid < 32)
        scores[block_row + tid] = sred[0][tid] + sred[1][tid] + sred[2][tid] + sred[3][tid] + b2[0];
}

// One block per segment: bounds via binary search (batch sorted), max (clamped >=0),
// exp-sum, then per-column weighted accumulation of x with 4-way unroll for MLP.
__global__ __launch_bounds__(256) void pool_kernel(
    const float* __restrict__ x, const int* __restrict__ batch,
    const float* __restrict__ scores, float* __restrict__ out)
{
    const int g    = blockIdx.x;
    const int tid  = threadIdx.x;
    const int lane = tid & 63;
    const int wave = tid >> 6;

    __shared__ int   s_bounds[2];
    __shared__ float red[4];

    if (tid < 2) {
        int target = g + tid;
        int lo = 0, hi = kN;
        while (lo < hi) {
            int mid = (lo + hi) >> 1;
            if (batch[mid] < target) lo = mid + 1; else hi = mid;
        }
        s_bounds[tid] = lo;
    }
    __syncthreads();
    const int lo = s_bounds[0], hi = s_bounds[1];

    // segment max, clamped at >= 0 (torch scatter-amax-into-zeros semantics)
    float m = 0.f;
    for (int i = lo + tid; i < hi; i += 256) m = fmaxf(m, scores[i]);
#pragma unroll
    for (int off = 32; off > 0; off >>= 1) m = fmaxf(m, __shfl_xor(m, off));
    if (lane == 0) red[wave] = m;
    __syncthreads();
    m = fmaxf(fmaxf(red[0], red[1]), fmaxf(red[2], red[3]));
    __syncthreads();

    // sum of exp
    float sum = 0.f;
    for (int i = lo + tid; i < hi; i += 256) sum += __expf(scores[i] - m);
#pragma unroll
    for (int off = 32; off > 0; off >>= 1) sum += __shfl_xor(sum, off);
    if (lane == 0) red[wave] = sum;
    __syncthreads();
    sum = red[0] + red[1] + red[2] + red[3];

    // weighted accumulation: thread owns column `tid`; 4-way unroll for memory ILP
    float acc0 = 0.f, acc1 = 0.f, acc2 = 0.f, acc3 = 0.f;
    int i = lo;
    for (; i + 4 <= hi; i += 4) {
        float w0 = __expf(scores[i + 0] - m);
        float w1 = __expf(scores[i + 1] - m);
        float w2 = __expf(scores[i + 2] - m);
        float w3 = __expf(scores[i + 3] - m);
        acc0 = fmaf(x[(size_t)(i + 0) * kD + tid], w0, acc0);
        acc1 = fmaf(x[(size_t)(i + 1) * kD + tid], w1, acc1);
        acc2 = fmaf(x[(size_t)(i + 2) * kD + tid], w2, acc2);
        acc3 = fmaf(x[(size_t)(i + 3) * kD + tid], w3, acc3);
    }
    for (; i < hi; ++i) {
        float w = __expf(scores[i] - m);
        acc0 = fmaf(x[(size_t)i * kD + tid], w, acc0);
    }
    float acc = (acc0 + acc1) + (acc2 + acc3);
    out[(size_t)g * kD + tid] = acc / (sum + 1e-9f);
}

extern "C" void kernel_launch(void* const* d_in, const int* in_sizes, int n_in,
                              void* d_out, int out_size, void* d_ws, size_t ws_size,
                              hipStream_t stream) {
    const float* x     = (const float*)d_in[0];
    const float* W1    = (const float*)d_in[1];
    const float* b1    = (const float*)d_in[2];
    const float* W2    = (const float*)d_in[3];
    const float* b2    = (const float*)d_in[4];
    const int*   batch = (const int*)d_in[5];
    float* out = (float*)d_out;

    unsigned short* packed = (unsigned short*)d_ws;              // 131072 B
    float* scores = (float*)((char*)d_ws + 131072);              // 1 MB

    pack_w1_kernel<<<32, 256, 0, stream>>>(W1, packed);
    score_kernel<<<kN / 32, 256, 0, stream>>>(x, packed, b1, W2, b2, scores);
    pool_kernel<<<kSeg, 256, 0, stream>>>(x, batch, scores, out);
}